// Round 10
// baseline (179.907 us; speedup 1.0000x reference)
//
#include <hip/hip_runtime.h>
#include <math.h>

// MMD loss. Z = concat(X,Y) [8192 x 256] fp32.
// Round 10: R9 (B-in-LDS) regressed: linear LDS layout -> 1.06M bank
//   conflicts + 66 KB LDS -> 2 blocks/CU + barrier drains. Reverted to R8's
//   proven direct-global dbuf kernel (76 us, 0 conflicts, no spill).
//   Single change: CHUNK 4 -> 1 (2080 blocks, 8.1/CU oversubscribed).
//   R6 vs R8 showed BW = inflight/latency with ~64 wave-loads in flight/CU
//   in both (7 TB/s); VGPR=128 permits 4 waves/SIMD -> 4 blocks/CU resident
//   (enforced via __launch_bounds__(256,4)), doubling in-flight bytes.
// Math (R5-R9 verified, absmax 0.0): 1-phase bf16 Gram, sq exact fp32;
//   d2 = sq_i + sq_j - 2 z_i.z_j; bandwidth analytic
//   (sum d2 = 2M*S - 2||sum z||^2); K = t+t^2+t^4+t^8+t^16, t=exp(-d2/(4bw));
//   out = (Sxx + Syy - Sxy_both)/n^2, fp64 accumulation.

#define N_HALF 4096
#define DIM 256
#define M_TOT 8192
#define TILE 128
#define NT 64
#define NT_HALF 32
#define NBLOCKS (NT * (NT + 1) / 2)  // 2080 = 8 * 260

typedef unsigned short ushort_t;
typedef __attribute__((ext_vector_type(8))) short short8;   // 8 bf16 = 4 VGPRs
typedef __attribute__((ext_vector_type(4))) float floatx4;  // MFMA C/D

// Fragment-swizzled bf16 Z (4 MB). For row-block rb (16 rows) and k-chunk kk
// (32 k): g_zf[rb*4096 + kk*512 + m*32 + q*8 + j] = Z[rb*16+m][kk*32+q*8+j].
// MFMA frag load (lane = q*16+m) reads 16 contiguous bytes; wave = 1 KB run.
__device__ ushort_t g_zf[M_TOT * DIM];

__device__ __forceinline__ ushort_t f2bf(float f) {  // RNE, finite inputs
    unsigned u = __float_as_uint(f);
    u += 0x7fffu + ((u >> 16) & 1u);
    return (ushort_t)(u >> 16);
}

__device__ __forceinline__ void load_frags(const ushort_t* aP, const ushort_t* bP,
                                           int kk, short8 (&af)[4], short8 (&bf)[4]) {
#pragma unroll
    for (int mi = 0; mi < 4; ++mi)
        af[mi] = *(const short8*)(aP + (size_t)mi * 4096 + kk * 512);
#pragma unroll
    for (int ni = 0; ni < 4; ++ni)
        bf[ni] = *(const short8*)(bP + (size_t)ni * 4096 + kk * 512);
}

__device__ __forceinline__ void mfma16(const short8 (&af)[4], const short8 (&bf)[4],
                                       floatx4 (&accv)[4][4]) {
#pragma unroll
    for (int mi = 0; mi < 4; ++mi)
#pragma unroll
        for (int ni = 0; ni < 4; ++ni)
            accv[mi][ni] = __builtin_amdgcn_mfma_f32_16x16x32_bf16(
                af[mi], bf[ni], accv[mi][ni], 0, 0, 0);
}

// ---------------- k_prep: convert(swizzled) + row norms + col sums -----------
// 128 blocks x 256 threads; wave w owns 16 rows; lane l owns cols [4l,4l+4).
__global__ __launch_bounds__(256) void k_prep(const float* __restrict__ X,
                                              const float* __restrict__ Y,
                                              float* __restrict__ sq,
                                              float* __restrict__ colsum_r,
                                              float* __restrict__ Ssum_r) {
    __shared__ float cpart[4][256];
    __shared__ float spart[4];
    const int t = threadIdx.x, wave = t >> 6, lane = t & 63;
    const int row0 = blockIdx.x * 64 + wave * 16;
    const int kk = lane >> 3, q = (lane >> 1) & 3, j0 = (lane & 1) * 4;
    float c0 = 0.f, c1 = 0.f, c2 = 0.f, c3 = 0.f, ssum = 0.f;
#pragma unroll 4
    for (int i = 0; i < 16; ++i) {
        const int row = row0 + i;
        const float* p = (row < N_HALF) ? (X + (size_t)row * DIM)
                                        : (Y + (size_t)(row - N_HALF) * DIM);
        const float4 v = *((const float4*)p + lane);
        ushort4 hi;
        hi.x = f2bf(v.x); hi.y = f2bf(v.y); hi.z = f2bf(v.z); hi.w = f2bf(v.w);
        const int rb = row >> 4, m = row & 15;
        *(ushort4*)(g_zf + (size_t)rb * 4096 + kk * 512 + m * 32 + q * 8 + j0) = hi;
        c0 += v.x; c1 += v.y; c2 += v.z; c3 += v.w;
        float s = fmaf(v.x, v.x, fmaf(v.y, v.y, fmaf(v.z, v.z, v.w * v.w)));
#pragma unroll
        for (int off = 32; off > 0; off >>= 1) s += __shfl_xor(s, off);
        if (lane == 0) sq[row] = s;
        ssum += s;  // butterfly left full sum in every lane
    }
    float4 cp; cp.x = c0; cp.y = c1; cp.z = c2; cp.w = c3;
    *(float4*)&cpart[wave][lane * 4] = cp;
    if (lane == 0) spart[wave] = ssum;
    __syncthreads();
    const float cs = cpart[0][t] + cpart[1][t] + cpart[2][t] + cpart[3][t];
    const int rep = blockIdx.x & 7;  // 8 replicas -> 16 adds/address
    atomicAdd(&colsum_r[rep * 256 + t], cs);  // poison -3e-13/rep: harmless
    if (t == 0) atomicAdd(&Ssum_r[rep], spart[0] + spart[1] + spart[2] + spart[3]);
}

// ---------------- k_gram: bandwidth + pipelined direct-MFMA Gram -------------
// 2080 blocks x 256 threads; one 128x128 tile per block; 4 blocks/CU resident.
__global__ __launch_bounds__(256, 4) void k_gram(const float* __restrict__ sq,
                                                 const float* __restrict__ colsum_r,
                                                 const float* __restrict__ Ssum_r,
                                                 double* __restrict__ acc,
                                                 unsigned* __restrict__ cnt,
                                                 float* __restrict__ out) {
    // XCD-band swizzle (2080 = 8*260): same-XCD blocks contiguous in triangle.
    const int bid = (int)blockIdx.x;
    const int b = (bid & 7) * 260 + (bid >> 3);

    __shared__ double redw[4][3];

    const int t = threadIdx.x;
    const int lane = t & 63, wave = t >> 6;
    const int l15 = lane & 15, quad = lane >> 4;
    const int wrow = (wave >> 1) * 64, wcol = (wave & 1) * 64;

    // ---- per-block bandwidth recompute from 8-replica partials ----
    {
        float csf = 0.f;
#pragma unroll
        for (int r = 0; r < 8; ++r) csf += colsum_r[r * 256 + t];
        double p = (double)csf * (double)csf;
#pragma unroll
        for (int off = 32; off > 0; off >>= 1) p += __shfl_xor(p, off);
        if (lane == 0) redw[wave][0] = p;
    }
    __syncthreads();
    const double SS = redw[0][0] + redw[1][0] + redw[2][0] + redw[3][0];
    float Sf = 0.f;
#pragma unroll
    for (int r = 0; r < 8; ++r) Sf += Ssum_r[r];
    const double sum_d2 = 2.0 * (double)M_TOT * (double)Sf - 2.0 * SS;
    const double bw = sum_d2 / ((double)M_TOT * (double)M_TOT - (double)M_TOT);
    const float c2 = (float)(1.4426950408889634 / (4.0 * bw));  // exp2 scale
    const float twoc2 = 2.f * c2;
    __syncthreads();  // redw free for reuse

    // triangular decode: b -> (ti, tj), tj >= ti
    int ti = (int)((129.0f - sqrtf(16641.0f - 8.0f * (float)b)) * 0.5f);
    if (ti < 0) ti = 0; if (ti > NT - 1) ti = NT - 1;
    while (ti * NT - ti * (ti - 1) / 2 > b) --ti;
    while ((ti + 1) * NT - (ti + 1) * ti / 2 <= b) ++ti;
    const int tj = ti + (b - (ti * NT - ti * (ti - 1) / 2));

    const int laneoff = l15 * 32 + quad * 8;
    const ushort_t* aP = g_zf + (size_t)(ti * 8 + (wrow >> 4)) * 4096 + laneoff;
    const ushort_t* bP = g_zf + (size_t)(tj * 8 + (wcol >> 4)) * 4096 + laneoff;

    floatx4 accv[4][4];
#pragma unroll
    for (int mi = 0; mi < 4; ++mi)
#pragma unroll
        for (int ni = 0; ni < 4; ++ni) accv[mi][ni] = (floatx4)0.f;

    short8 af0[4], bf0[4], af1[4], bf1[4];
    load_frags(aP, bP, 0, af0, bf0);  // prime kk=0
#pragma unroll
    for (int kk = 0; kk < 8; kk += 2) {
        load_frags(aP, bP, kk + 1, af1, bf1);   // in flight over mfma kk
        mfma16(af0, bf0, accv);
        if (kk + 2 < 8) load_frags(aP, bP, kk + 2, af0, bf0);
        mfma16(af1, bf1, accv);
    }

    // ---- epilogue. C/D: col = lane&15, row = quad*4 + reg. ----
    const int arow0 = ti * TILE, brow0 = tj * TILE;
    float nsj[4];
#pragma unroll
    for (int ni = 0; ni < 4; ++ni)
        nsj[ni] = -c2 * sq[brow0 + wcol + ni * 16 + l15];
    floatx4 nsi4[4];
#pragma unroll
    for (int mi = 0; mi < 4; ++mi) {
        const float4 sv = *(const float4*)&sq[arow0 + wrow + mi * 16 + quad * 4];
        nsi4[mi][0] = -c2 * sv.x; nsi4[mi][1] = -c2 * sv.y;
        nsi4[mi][2] = -c2 * sv.z; nsi4[mi][3] = -c2 * sv.w;
    }
    floatx4 sum4 = (floatx4)0.f;
#pragma unroll
    for (int mi = 0; mi < 4; ++mi) {
#pragma unroll
        for (int ni = 0; ni < 4; ++ni) {
            const floatx4 addv = nsi4[mi] + (floatx4)nsj[ni];
            floatx4 arg = twoc2 * accv[mi][ni] + addv;
            floatx4 tt;
#pragma unroll
            for (int r = 0; r < 4; ++r) tt[r] = exp2f(fminf(arg[r], 0.f));
            const floatx4 t2 = tt * tt, t4 = t2 * t2, t8 = t4 * t4, t16 = t8 * t8;
            sum4 += (tt + t2) + (t4 + t8) + t16;
        }
    }
    const float fsum = (sum4[0] + sum4[1]) + (sum4[2] + sum4[3]);
    const double contrib = ((ti == tj) ? 1.0 : 2.0) * (double)fsum;
    double lxx = 0.0, lxy = 0.0, lyy = 0.0;
    if (tj < NT_HALF)       lxx = contrib;   // block-uniform branches
    else if (ti < NT_HALF)  lxy = contrib;
    else                    lyy = contrib;

    // ---- block reduction + finalize ----
#pragma unroll
    for (int off = 32; off > 0; off >>= 1) {
        lxx += __shfl_xor(lxx, off);
        lxy += __shfl_xor(lxy, off);
        lyy += __shfl_xor(lyy, off);
    }
    if (lane == 0) { redw[wave][0] = lxx; redw[wave][1] = lxy; redw[wave][2] = lyy; }
    __syncthreads();
    if (t == 0) {
        double sxx = 0.0, sxy = 0.0, syy = 0.0;
#pragma unroll
        for (int wv = 0; wv < 4; ++wv) {
            sxx += redw[wv][0]; sxy += redw[wv][1]; syy += redw[wv][2];
        }
        if (sxx != 0.0) atomicAdd(&acc[0], sxx);
        if (sxy != 0.0) atomicAdd(&acc[1], sxy);
        if (syy != 0.0) atomicAdd(&acc[2], syy);
        __threadfence();  // release region adds before counter bump
        const unsigned old = atomicAdd(cnt, 1u);
        // counter starts at 0xAAAAAAAA (ws poison) or 0 — accept either
        if (old == (0xAAAAAAAAu + (unsigned)(NBLOCKS - 1)) ||
            old == (unsigned)(NBLOCKS - 1)) {
            const double xx = atomicAdd(&acc[0], 0.0);  // coherent reads
            const double xy = atomicAdd(&acc[1], 0.0);
            const double yy = atomicAdd(&acc[2], 0.0);
            out[0] = (float)((xx + yy - xy) *
                             (1.0 / ((double)N_HALF * (double)N_HALF)));
        }
    }
}

extern "C" void kernel_launch(void* const* d_in, const int* in_sizes, int n_in,
                              void* d_out, int out_size, void* d_ws, size_t ws_size,
                              hipStream_t stream) {
    const float* X = (const float*)d_in[0];
    const float* Y = (const float*)d_in[1];
    char* ws = (char*)d_ws;
    float* sq        = (float*)ws;               // 8192 f32  [0, 32768)
    float* colsum_r  = (float*)(ws + 32768);     // 8*256 f32 [32768, 40960)
    float* Ssum_r    = (float*)(ws + 40960);     // 8 f32     [40960, 40992)
    unsigned* cnt    = (unsigned*)(ws + 40992);  // 1 u32
    double* acc      = (double*)(ws + 41000);    // 3 f64 (8-aligned)
    float* out = (float*)d_out;

    hipLaunchKernelGGL(k_prep, dim3(128), dim3(256), 0, stream,
                       X, Y, sq, colsum_r, Ssum_r);
    hipLaunchKernelGGL(k_gram, dim3(NBLOCKS), dim3(256), 0, stream,
                       sq, colsum_r, Ssum_r, acc, cnt, out);
}

// Round 11
// 160.042 us; speedup vs baseline: 1.1241x; 1.1241x over previous
//
#include <hip/hip_runtime.h>
#include <math.h>

// MMD loss. Z = concat(X,Y) [8192 x 256] fp32.
// Round 11: the R10 experiment, done right. R10's __launch_bounds__(256,4)
//   pinned the allocator to 64 VGPR -> 54 MB spill (R7's failure, opposite
//   trigger). This round: R8's exact inner loop (VGPR=128, no spill, 76 us)
//   with CHUNK=1 (2080 blocks = 8.1/CU oversubscribed) and PLAIN
//   __launch_bounds__(256) — 128 VGPR naturally allows 4 waves/SIMD ->
//   4 blocks/CU resident, ~2x in-flight bytes vs R8 (BW = inflight/latency).
// Math (R5-R10 verified, absmax 0.0): 1-phase bf16 Gram, sq exact fp32;
//   d2 = sq_i + sq_j - 2 z_i.z_j; bandwidth analytic
//   (sum d2 = 2M*S - 2||sum z||^2); K = t+t^2+t^4+t^8+t^16, t=exp(-d2/(4bw));
//   out = (Sxx + Syy - Sxy_both)/n^2, fp64 accumulation.

#define N_HALF 4096
#define DIM 256
#define M_TOT 8192
#define TILE 128
#define NT 64
#define NT_HALF 32
#define NBLOCKS (NT * (NT + 1) / 2)  // 2080 = 8 * 260

typedef unsigned short ushort_t;
typedef __attribute__((ext_vector_type(8))) short short8;   // 8 bf16 = 4 VGPRs
typedef __attribute__((ext_vector_type(4))) float floatx4;  // MFMA C/D

// Fragment-swizzled bf16 Z (4 MB). For row-block rb (16 rows) and k-chunk kk
// (32 k): g_zf[rb*4096 + kk*512 + m*32 + q*8 + j] = Z[rb*16+m][kk*32+q*8+j].
// MFMA frag load (lane = q*16+m) reads 16 contiguous bytes; wave = 1 KB run.
__device__ ushort_t g_zf[M_TOT * DIM];

__device__ __forceinline__ ushort_t f2bf(float f) {  // RNE, finite inputs
    unsigned u = __float_as_uint(f);
    u += 0x7fffu + ((u >> 16) & 1u);
    return (ushort_t)(u >> 16);
}

__device__ __forceinline__ void load_frags(const ushort_t* aP, const ushort_t* bP,
                                           int kk, short8 (&af)[4], short8 (&bf)[4]) {
#pragma unroll
    for (int mi = 0; mi < 4; ++mi)
        af[mi] = *(const short8*)(aP + (size_t)mi * 4096 + kk * 512);
#pragma unroll
    for (int ni = 0; ni < 4; ++ni)
        bf[ni] = *(const short8*)(bP + (size_t)ni * 4096 + kk * 512);
}

__device__ __forceinline__ void mfma16(const short8 (&af)[4], const short8 (&bf)[4],
                                       floatx4 (&accv)[4][4]) {
#pragma unroll
    for (int mi = 0; mi < 4; ++mi)
#pragma unroll
        for (int ni = 0; ni < 4; ++ni)
            accv[mi][ni] = __builtin_amdgcn_mfma_f32_16x16x32_bf16(
                af[mi], bf[ni], accv[mi][ni], 0, 0, 0);
}

// ---------------- k_prep: convert(swizzled) + row norms + col sums -----------
// 128 blocks x 256 threads; wave w owns 16 rows; lane l owns cols [4l,4l+4).
__global__ __launch_bounds__(256) void k_prep(const float* __restrict__ X,
                                              const float* __restrict__ Y,
                                              float* __restrict__ sq,
                                              float* __restrict__ colsum_r,
                                              float* __restrict__ Ssum_r) {
    __shared__ float cpart[4][256];
    __shared__ float spart[4];
    const int t = threadIdx.x, wave = t >> 6, lane = t & 63;
    const int row0 = blockIdx.x * 64 + wave * 16;
    const int kk = lane >> 3, q = (lane >> 1) & 3, j0 = (lane & 1) * 4;
    float c0 = 0.f, c1 = 0.f, c2 = 0.f, c3 = 0.f, ssum = 0.f;
#pragma unroll 4
    for (int i = 0; i < 16; ++i) {
        const int row = row0 + i;
        const float* p = (row < N_HALF) ? (X + (size_t)row * DIM)
                                        : (Y + (size_t)(row - N_HALF) * DIM);
        const float4 v = *((const float4*)p + lane);
        ushort4 hi;
        hi.x = f2bf(v.x); hi.y = f2bf(v.y); hi.z = f2bf(v.z); hi.w = f2bf(v.w);
        const int rb = row >> 4, m = row & 15;
        *(ushort4*)(g_zf + (size_t)rb * 4096 + kk * 512 + m * 32 + q * 8 + j0) = hi;
        c0 += v.x; c1 += v.y; c2 += v.z; c3 += v.w;
        float s = fmaf(v.x, v.x, fmaf(v.y, v.y, fmaf(v.z, v.z, v.w * v.w)));
#pragma unroll
        for (int off = 32; off > 0; off >>= 1) s += __shfl_xor(s, off);
        if (lane == 0) sq[row] = s;
        ssum += s;  // butterfly left full sum in every lane
    }
    float4 cp; cp.x = c0; cp.y = c1; cp.z = c2; cp.w = c3;
    *(float4*)&cpart[wave][lane * 4] = cp;
    if (lane == 0) spart[wave] = ssum;
    __syncthreads();
    const float cs = cpart[0][t] + cpart[1][t] + cpart[2][t] + cpart[3][t];
    const int rep = blockIdx.x & 7;  // 8 replicas -> 16 adds/address
    atomicAdd(&colsum_r[rep * 256 + t], cs);  // poison -3e-13/rep: harmless
    if (t == 0) atomicAdd(&Ssum_r[rep], spart[0] + spart[1] + spart[2] + spart[3]);
}

// ---------------- k_gram: bandwidth + pipelined direct-MFMA Gram -------------
// 2080 blocks x 256 threads; one 128x128 tile per block. Plain launch bounds:
// compiler lands ~128 VGPR (R7/R8 evidence) -> 4 blocks/CU resident.
__global__ __launch_bounds__(256) void k_gram(const float* __restrict__ sq,
                                              const float* __restrict__ colsum_r,
                                              const float* __restrict__ Ssum_r,
                                              double* __restrict__ acc,
                                              unsigned* __restrict__ cnt,
                                              float* __restrict__ out) {
    // XCD-band swizzle (2080 = 8*260): same-XCD blocks contiguous in triangle.
    const int bid = (int)blockIdx.x;
    const int b = (bid & 7) * 260 + (bid >> 3);

    __shared__ double redw[4][3];

    const int t = threadIdx.x;
    const int lane = t & 63, wave = t >> 6;
    const int l15 = lane & 15, quad = lane >> 4;
    const int wrow = (wave >> 1) * 64, wcol = (wave & 1) * 64;

    // ---- per-block bandwidth recompute from 8-replica partials ----
    {
        float csf = 0.f;
#pragma unroll
        for (int r = 0; r < 8; ++r) csf += colsum_r[r * 256 + t];
        double p = (double)csf * (double)csf;
#pragma unroll
        for (int off = 32; off > 0; off >>= 1) p += __shfl_xor(p, off);
        if (lane == 0) redw[wave][0] = p;
    }
    __syncthreads();
    const double SS = redw[0][0] + redw[1][0] + redw[2][0] + redw[3][0];
    float Sf = 0.f;
#pragma unroll
    for (int r = 0; r < 8; ++r) Sf += Ssum_r[r];
    const double sum_d2 = 2.0 * (double)M_TOT * (double)Sf - 2.0 * SS;
    const double bw = sum_d2 / ((double)M_TOT * (double)M_TOT - (double)M_TOT);
    const float c2 = (float)(1.4426950408889634 / (4.0 * bw));  // exp2 scale
    const float twoc2 = 2.f * c2;
    __syncthreads();  // redw free for reuse

    // triangular decode: b -> (ti, tj), tj >= ti
    int ti = (int)((129.0f - sqrtf(16641.0f - 8.0f * (float)b)) * 0.5f);
    if (ti < 0) ti = 0; if (ti > NT - 1) ti = NT - 1;
    while (ti * NT - ti * (ti - 1) / 2 > b) --ti;
    while ((ti + 1) * NT - (ti + 1) * ti / 2 <= b) ++ti;
    const int tj = ti + (b - (ti * NT - ti * (ti - 1) / 2));

    const int laneoff = l15 * 32 + quad * 8;
    const ushort_t* aP = g_zf + (size_t)(ti * 8 + (wrow >> 4)) * 4096 + laneoff;
    const ushort_t* bP = g_zf + (size_t)(tj * 8 + (wcol >> 4)) * 4096 + laneoff;

    floatx4 accv[4][4];
#pragma unroll
    for (int mi = 0; mi < 4; ++mi)
#pragma unroll
        for (int ni = 0; ni < 4; ++ni) accv[mi][ni] = (floatx4)0.f;

    short8 af0[4], bf0[4], af1[4], bf1[4];
    load_frags(aP, bP, 0, af0, bf0);  // prime kk=0
#pragma unroll
    for (int kk = 0; kk < 8; kk += 2) {
        load_frags(aP, bP, kk + 1, af1, bf1);   // in flight over mfma kk
        mfma16(af0, bf0, accv);
        if (kk + 2 < 8) load_frags(aP, bP, kk + 2, af0, bf0);
        mfma16(af1, bf1, accv);
    }

    // ---- epilogue. C/D: col = lane&15, row = quad*4 + reg. ----
    const int arow0 = ti * TILE, brow0 = tj * TILE;
    float nsj[4];
#pragma unroll
    for (int ni = 0; ni < 4; ++ni)
        nsj[ni] = -c2 * sq[brow0 + wcol + ni * 16 + l15];
    floatx4 nsi4[4];
#pragma unroll
    for (int mi = 0; mi < 4; ++mi) {
        const float4 sv = *(const float4*)&sq[arow0 + wrow + mi * 16 + quad * 4];
        nsi4[mi][0] = -c2 * sv.x; nsi4[mi][1] = -c2 * sv.y;
        nsi4[mi][2] = -c2 * sv.z; nsi4[mi][3] = -c2 * sv.w;
    }
    floatx4 sum4 = (floatx4)0.f;
#pragma unroll
    for (int mi = 0; mi < 4; ++mi) {
#pragma unroll
        for (int ni = 0; ni < 4; ++ni) {
            const floatx4 addv = nsi4[mi] + (floatx4)nsj[ni];
            floatx4 arg = twoc2 * accv[mi][ni] + addv;
            floatx4 tt;
#pragma unroll
            for (int r = 0; r < 4; ++r) tt[r] = exp2f(fminf(arg[r], 0.f));
            const floatx4 t2 = tt * tt, t4 = t2 * t2, t8 = t4 * t4, t16 = t8 * t8;
            sum4 += (tt + t2) + (t4 + t8) + t16;
        }
    }
    const float fsum = (sum4[0] + sum4[1]) + (sum4[2] + sum4[3]);
    const double contrib = ((ti == tj) ? 1.0 : 2.0) * (double)fsum;
    double lxx = 0.0, lxy = 0.0, lyy = 0.0;
    if (tj < NT_HALF)       lxx = contrib;   // block-uniform branches
    else if (ti < NT_HALF)  lxy = contrib;
    else                    lyy = contrib;

    // ---- block reduction + finalize ----
#pragma unroll
    for (int off = 32; off > 0; off >>= 1) {
        lxx += __shfl_xor(lxx, off);
        lxy += __shfl_xor(lxy, off);
        lyy += __shfl_xor(lyy, off);
    }
    if (lane == 0) { redw[wave][0] = lxx; redw[wave][1] = lxy; redw[wave][2] = lyy; }
    __syncthreads();
    if (t == 0) {
        double sxx = 0.0, sxy = 0.0, syy = 0.0;
#pragma unroll
        for (int wv = 0; wv < 4; ++wv) {
            sxx += redw[wv][0]; sxy += redw[wv][1]; syy += redw[wv][2];
        }
        if (sxx != 0.0) atomicAdd(&acc[0], sxx);
        if (sxy != 0.0) atomicAdd(&acc[1], sxy);
        if (syy != 0.0) atomicAdd(&acc[2], syy);
        __threadfence();  // release region adds before counter bump
        const unsigned old = atomicAdd(cnt, 1u);
        // counter starts at 0xAAAAAAAA (ws poison) or 0 — accept either
        if (old == (0xAAAAAAAAu + (unsigned)(NBLOCKS - 1)) ||
            old == (unsigned)(NBLOCKS - 1)) {
            const double xx = atomicAdd(&acc[0], 0.0);  // coherent reads
            const double xy = atomicAdd(&acc[1], 0.0);
            const double yy = atomicAdd(&acc[2], 0.0);
            out[0] = (float)((xx + yy - xy) *
                             (1.0 / ((double)N_HALF * (double)N_HALF)));
        }
    }
}

extern "C" void kernel_launch(void* const* d_in, const int* in_sizes, int n_in,
                              void* d_out, int out_size, void* d_ws, size_t ws_size,
                              hipStream_t stream) {
    const float* X = (const float*)d_in[0];
    const float* Y = (const float*)d_in[1];
    char* ws = (char*)d_ws;
    float* sq        = (float*)ws;               // 8192 f32  [0, 32768)
    float* colsum_r  = (float*)(ws + 32768);     // 8*256 f32 [32768, 40960)
    float* Ssum_r    = (float*)(ws + 40960);     // 8 f32     [40960, 40992)
    unsigned* cnt    = (unsigned*)(ws + 40992);  // 1 u32
    double* acc      = (double*)(ws + 41000);    // 3 f64 (8-aligned)
    float* out = (float*)d_out;

    hipLaunchKernelGGL(k_prep, dim3(128), dim3(256), 0, stream,
                       X, Y, sq, colsum_r, Ssum_r);
    hipLaunchKernelGGL(k_gram, dim3(NBLOCKS), dim3(256), 0, stream,
                       sq, colsum_r, Ssum_r, acc, cnt, out);
}

// Round 12
// 148.821 us; speedup vs baseline: 1.2089x; 1.0754x over previous
//
#include <hip/hip_runtime.h>
#include <math.h>

// MMD loss. Z = concat(X,Y) [8192 x 256] fp32.
// Round 12: attack the measured ~600-900 cyc remote-XCD load latency.
//   g_zf (4 MB) is REPLICATED 8x (64 MB); k_prep writes all copies; each
//   k_gram block reads copy (bid&7) == its own XCD under round-robin dispatch
//   -> fragment loads become local-L2 hits (~200 cyc, no fabric). Wrong
//   mapping = today's remote behavior (perf-only risk).
//   Per-block bandwidth prologue hoisted into tiny k_bw kernel (k_gram reads
//   one scalar cconst[0]; R6-R11 showed launch count doesn't move the ~60 us
//   non-gram floor, but the per-block prologue cost ~1 us x blocks/CU).
//   CHUNK=2 (1040 blocks = 4.06/CU): block-boundary overlap now that
//   per-block fixed cost is ~zero; keeps 2-tile A locality. R8 dbuf K-loop
//   kept verbatim (VGPR 128-144, no spill).
// Math (R5-R11 verified, absmax 0.0): 1-phase bf16 Gram, sq exact fp32;
//   d2 = sq_i + sq_j - 2 z_i.z_j; bandwidth analytic
//   (sum d2 = 2M*S - 2||sum z||^2); K = t+t^2+t^4+t^8+t^16, t=exp(-d2/(4bw));
//   out = (Sxx + Syy - Sxy_both)/n^2, fp64 accumulation.

#define N_HALF 4096
#define DIM 256
#define M_TOT 8192
#define TILE 128
#define NT 64
#define NT_HALF 32
#define CHUNK 2
#define NCHUNK 1040  // 2080 tiles / 2; 1040 = 8 * 130

typedef unsigned short ushort_t;
typedef __attribute__((ext_vector_type(8))) short short8;   // 8 bf16 = 4 VGPRs
typedef __attribute__((ext_vector_type(4))) float floatx4;  // MFMA C/D

// Fragment-swizzled bf16 Z, replicated per XCD (8 x 4 MB). For row-block rb
// (16 rows), k-chunk kk (32 k): zf[rb*4096 + kk*512 + m*32 + q*8 + j] =
// Z[rb*16+m][kk*32+q*8+j]. Frag load (lane=q*16+m) = 16 contiguous bytes.
__device__ ushort_t g_zf[8][M_TOT * DIM];

__device__ __forceinline__ ushort_t f2bf(float f) {  // RNE, finite inputs
    unsigned u = __float_as_uint(f);
    u += 0x7fffu + ((u >> 16) & 1u);
    return (ushort_t)(u >> 16);
}

__device__ __forceinline__ void load_frags(const ushort_t* aP, const ushort_t* bP,
                                           int kk, short8 (&af)[4], short8 (&bf)[4]) {
#pragma unroll
    for (int mi = 0; mi < 4; ++mi)
        af[mi] = *(const short8*)(aP + (size_t)mi * 4096 + kk * 512);
#pragma unroll
    for (int ni = 0; ni < 4; ++ni)
        bf[ni] = *(const short8*)(bP + (size_t)ni * 4096 + kk * 512);
}

__device__ __forceinline__ void mfma16(const short8 (&af)[4], const short8 (&bf)[4],
                                       floatx4 (&accv)[4][4]) {
#pragma unroll
    for (int mi = 0; mi < 4; ++mi)
#pragma unroll
        for (int ni = 0; ni < 4; ++ni)
            accv[mi][ni] = __builtin_amdgcn_mfma_f32_16x16x32_bf16(
                af[mi], bf[ni], accv[mi][ni], 0, 0, 0);
}

// ---------------- k_prep: convert + replicate x8 + row norms + col sums ------
__global__ __launch_bounds__(256) void k_prep(const float* __restrict__ X,
                                              const float* __restrict__ Y,
                                              float* __restrict__ sq,
                                              float* __restrict__ colsum_r,
                                              float* __restrict__ Ssum_r) {
    __shared__ float cpart[4][256];
    __shared__ float spart[4];
    const int t = threadIdx.x, wave = t >> 6, lane = t & 63;
    const int row0 = blockIdx.x * 64 + wave * 16;
    const int kk = lane >> 3, q = (lane >> 1) & 3, j0 = (lane & 1) * 4;
    float c0 = 0.f, c1 = 0.f, c2 = 0.f, c3 = 0.f, ssum = 0.f;
#pragma unroll 4
    for (int i = 0; i < 16; ++i) {
        const int row = row0 + i;
        const float* p = (row < N_HALF) ? (X + (size_t)row * DIM)
                                        : (Y + (size_t)(row - N_HALF) * DIM);
        const float4 v = *((const float4*)p + lane);
        ushort4 hi;
        hi.x = f2bf(v.x); hi.y = f2bf(v.y); hi.z = f2bf(v.z); hi.w = f2bf(v.w);
        const int rb = row >> 4, m = row & 15;
        const size_t off = (size_t)rb * 4096 + kk * 512 + m * 32 + q * 8 + j0;
#pragma unroll
        for (int c = 0; c < 8; ++c)  // replicate to every XCD's copy
            *(ushort4*)(&g_zf[c][off]) = hi;
        c0 += v.x; c1 += v.y; c2 += v.z; c3 += v.w;
        float s = fmaf(v.x, v.x, fmaf(v.y, v.y, fmaf(v.z, v.z, v.w * v.w)));
#pragma unroll
        for (int o = 32; o > 0; o >>= 1) s += __shfl_xor(s, o);
        if (lane == 0) sq[row] = s;
        ssum += s;  // butterfly left full sum in every lane
    }
    float4 cp; cp.x = c0; cp.y = c1; cp.z = c2; cp.w = c3;
    *(float4*)&cpart[wave][lane * 4] = cp;
    if (lane == 0) spart[wave] = ssum;
    __syncthreads();
    const float cs = cpart[0][t] + cpart[1][t] + cpart[2][t] + cpart[3][t];
    const int rep = blockIdx.x & 7;  // 8 replicas -> 16 adds/address
    atomicAdd(&colsum_r[rep * 256 + t], cs);  // poison -3e-13/rep: harmless
    if (t == 0) atomicAdd(&Ssum_r[rep], spart[0] + spart[1] + spart[2] + spart[3]);
}

// ---------------- k_bw: bandwidth scalar (1 block) ---------------------------
__global__ __launch_bounds__(256) void k_bw(const float* __restrict__ colsum_r,
                                            const float* __restrict__ Ssum_r,
                                            float* __restrict__ cconst) {
    __shared__ double red[4];
    const int t = threadIdx.x, lane = t & 63, wave = t >> 6;
    float csf = 0.f;
#pragma unroll
    for (int r = 0; r < 8; ++r) csf += colsum_r[r * 256 + t];
    double p = (double)csf * (double)csf;
#pragma unroll
    for (int o = 32; o > 0; o >>= 1) p += __shfl_xor(p, o);
    if (lane == 0) red[wave] = p;
    __syncthreads();
    if (t == 0) {
        const double SS = red[0] + red[1] + red[2] + red[3];
        float Sf = 0.f;
#pragma unroll
        for (int r = 0; r < 8; ++r) Sf += Ssum_r[r];
        const double sum_d2 = 2.0 * (double)M_TOT * (double)Sf - 2.0 * SS;
        const double bw = sum_d2 / ((double)M_TOT * (double)M_TOT - (double)M_TOT);
        cconst[0] = (float)(1.4426950408889634 / (4.0 * bw));  // exp2 scale
    }
}

// ---------------- k_gram: local-copy direct-MFMA Gram + finalize -------------
// 1040 blocks x 256 threads; 2 consecutive flat-triangle tiles per block.
__global__ __launch_bounds__(256) void k_gram(const float* __restrict__ sq,
                                              const float* __restrict__ cconst,
                                              double* __restrict__ acc,
                                              unsigned* __restrict__ cnt,
                                              float* __restrict__ out) {
    const int bid = (int)blockIdx.x;
    const ushort_t* zf = g_zf[bid & 7];  // local-XCD copy under round-robin
    // XCD-band swizzle (1040 = 8*130): same-XCD blocks contiguous in triangle.
    const int cc = (bid & 7) * 130 + (bid >> 3);
    const int f0 = cc * CHUNK;

    __shared__ double redw[4][3];

    const int t = threadIdx.x;
    const int lane = t & 63, wave = t >> 6;
    const int l15 = lane & 15, quad = lane >> 4;
    const int wrow = (wave >> 1) * 64, wcol = (wave & 1) * 64;

    const float c2 = cconst[0];  // one scalar load; no prologue barriers
    const float twoc2 = 2.f * c2;

    // triangular decode of f0 -> (ti, tj), tj >= ti
    int ti = (int)((129.0f - sqrtf(16641.0f - 8.0f * (float)f0)) * 0.5f);
    if (ti < 0) ti = 0; if (ti > NT - 1) ti = NT - 1;
    while (ti * NT - ti * (ti - 1) / 2 > f0) --ti;
    while ((ti + 1) * NT - (ti + 1) * ti / 2 <= f0) ++ti;
    int tj = ti + (f0 - (ti * NT - ti * (ti - 1) / 2));

    const int laneoff = l15 * 32 + quad * 8;
    const ushort_t* aP = zf + (size_t)(ti * 8 + (wrow >> 4)) * 4096 + laneoff;
    const ushort_t* bP = zf + (size_t)(tj * 8 + (wcol >> 4)) * 4096 + laneoff;

    short8 af0[4], bf0[4], af1[4], bf1[4];
    load_frags(aP, bP, 0, af0, bf0);  // prime tile 0, kk=0

    double lxx = 0.0, lxy = 0.0, lyy = 0.0;

#pragma unroll
    for (int s = 0; s < CHUNK; ++s) {
        floatx4 accv[4][4];
#pragma unroll
        for (int mi = 0; mi < 4; ++mi)
#pragma unroll
            for (int ni = 0; ni < 4; ++ni) accv[mi][ni] = (floatx4)0.f;

#pragma unroll
        for (int kk = 0; kk < 8; kk += 2) {
            load_frags(aP, bP, kk + 1, af1, bf1);   // in flight over mfma kk
            mfma16(af0, bf0, accv);
            if (kk + 2 < 8) load_frags(aP, bP, kk + 2, af0, bf0);
            mfma16(af1, bf1, accv);
        }

        const int cti = ti, ctj = tj;
        if (s < CHUNK - 1) {
            ++tj; if (tj == NT) { ++ti; tj = ti; }
            aP = zf + (size_t)(ti * 8 + (wrow >> 4)) * 4096 + laneoff;
            bP = zf + (size_t)(tj * 8 + (wcol >> 4)) * 4096 + laneoff;
            load_frags(aP, bP, 0, af0, bf0);  // prefetch over epilogue
        }

        // ---- epilogue for (cti, ctj). C/D: col = lane&15, row = quad*4+reg.
        const int arow0 = cti * TILE, brow0 = ctj * TILE;
        float nsj[4];
#pragma unroll
        for (int ni = 0; ni < 4; ++ni)
            nsj[ni] = -c2 * sq[brow0 + wcol + ni * 16 + l15];
        floatx4 nsi4[4];
#pragma unroll
        for (int mi = 0; mi < 4; ++mi) {
            const float4 sv = *(const float4*)&sq[arow0 + wrow + mi * 16 + quad * 4];
            nsi4[mi][0] = -c2 * sv.x; nsi4[mi][1] = -c2 * sv.y;
            nsi4[mi][2] = -c2 * sv.z; nsi4[mi][3] = -c2 * sv.w;
        }
        floatx4 sum4 = (floatx4)0.f;
#pragma unroll
        for (int mi = 0; mi < 4; ++mi) {
#pragma unroll
            for (int ni = 0; ni < 4; ++ni) {
                const floatx4 addv = nsi4[mi] + (floatx4)nsj[ni];
                floatx4 arg = twoc2 * accv[mi][ni] + addv;
                floatx4 tt;
#pragma unroll
                for (int r = 0; r < 4; ++r) tt[r] = exp2f(fminf(arg[r], 0.f));
                const floatx4 t2 = tt * tt, t4 = t2 * t2, t8 = t4 * t4, t16 = t8 * t8;
                sum4 += (tt + t2) + (t4 + t8) + t16;
            }
        }
        const float fsum = (sum4[0] + sum4[1]) + (sum4[2] + sum4[3]);
        const double contrib = ((cti == ctj) ? 1.0 : 2.0) * (double)fsum;
        if (ctj < NT_HALF)       lxx += contrib;   // block-uniform branches
        else if (cti < NT_HALF)  lxy += contrib;
        else                     lyy += contrib;
    }

    // ---- block reduction + finalize ----
#pragma unroll
    for (int off = 32; off > 0; off >>= 1) {
        lxx += __shfl_xor(lxx, off);
        lxy += __shfl_xor(lxy, off);
        lyy += __shfl_xor(lyy, off);
    }
    if (lane == 0) { redw[wave][0] = lxx; redw[wave][1] = lxy; redw[wave][2] = lyy; }
    __syncthreads();
    if (t == 0) {
        double sxx = 0.0, sxy = 0.0, syy = 0.0;
#pragma unroll
        for (int wv = 0; wv < 4; ++wv) {
            sxx += redw[wv][0]; sxy += redw[wv][1]; syy += redw[wv][2];
        }
        if (sxx != 0.0) atomicAdd(&acc[0], sxx);
        if (sxy != 0.0) atomicAdd(&acc[1], sxy);
        if (syy != 0.0) atomicAdd(&acc[2], syy);
        __threadfence();  // release region adds before counter bump
        const unsigned old = atomicAdd(cnt, 1u);
        // counter starts at 0xAAAAAAAA (ws poison) or 0 — accept either
        if (old == (0xAAAAAAAAu + (unsigned)(NCHUNK - 1)) ||
            old == (unsigned)(NCHUNK - 1)) {
            const double xx = atomicAdd(&acc[0], 0.0);  // coherent reads
            const double xy = atomicAdd(&acc[1], 0.0);
            const double yy = atomicAdd(&acc[2], 0.0);
            out[0] = (float)((xx + yy - xy) *
                             (1.0 / ((double)N_HALF * (double)N_HALF)));
        }
    }
}

extern "C" void kernel_launch(void* const* d_in, const int* in_sizes, int n_in,
                              void* d_out, int out_size, void* d_ws, size_t ws_size,
                              hipStream_t stream) {
    const float* X = (const float*)d_in[0];
    const float* Y = (const float*)d_in[1];
    char* ws = (char*)d_ws;
    float* sq        = (float*)ws;               // 8192 f32  [0, 32768)
    float* colsum_r  = (float*)(ws + 32768);     // 8*256 f32 [32768, 40960)
    float* Ssum_r    = (float*)(ws + 40960);     // 8 f32     [40960, 40992)
    unsigned* cnt    = (unsigned*)(ws + 40992);  // 1 u32
    double* acc      = (double*)(ws + 41000);    // 3 f64 (8-aligned)
    float* cconst    = (float*)(ws + 41024);     // 1 f32
    float* out = (float*)d_out;

    hipLaunchKernelGGL(k_prep, dim3(128), dim3(256), 0, stream,
                       X, Y, sq, colsum_r, Ssum_r);
    hipLaunchKernelGGL(k_bw, dim3(1), dim3(256), 0, stream,
                       colsum_r, Ssum_r, cconst);
    hipLaunchKernelGGL(k_gram, dim3(NCHUNK), dim3(256), 0, stream,
                       sq, cconst, acc, cnt, out);
}

// Round 13
// 145.498 us; speedup vs baseline: 1.2365x; 1.0228x over previous
//
#include <hip/hip_runtime.h>
#include <math.h>

// MMD loss. Z = concat(X,Y) [8192 x 256] fp32.
// Round 13: consolidated finding from R3/R6/R8/R11/R12 — per-CU global-read
//   rate is pinned at ~24-27 GB/s/CU (MSHR/outstanding-line cap) regardless
//   of occupancy, MLP, staging style, or data placement. Only lever: fewer
//   unique bytes. 256x256 tiles cut issued bytes 532 MB -> 135 MB (4x tile
//   area per byte): 528 blocks x 512 threads, K-chunk=64 double-buffered in
//   LDS (2 x 64 KB -> 1 block/CU), linear global_load_lds staging (fragment
//   layout is DMA-legal), accv in registers (launch_bounds(512,2) grants 256
//   VGPR - R7's silent 128-cap spill avoided). Staging:compute = 10:1, so
//   barrier drains are absorbed by the rate-bound staging stream.
//   k_prep back to single g_zf copy (R12 replication: no effect).
// Math (R5-R12 verified, absmax 0.0): 1-phase bf16 Gram, sq exact fp32;
//   d2 = sq_i + sq_j - 2 z_i.z_j; bandwidth analytic
//   (sum d2 = 2M*S - 2||sum z||^2); K = t+t^2+t^4+t^8+t^16, t=exp(-d2/(4bw));
//   out = (Sxx + Syy - Sxy_both)/n^2, fp64 accumulation.

#define N_HALF 4096
#define DIM 256
#define M_TOT 8192
#define TILE2 256
#define NT2 32
#define NT2_HALF 16
#define NB2 (NT2 * (NT2 + 1) / 2)  // 528 = 8 * 66

typedef unsigned short ushort_t;
typedef __attribute__((ext_vector_type(8))) short short8;   // 8 bf16 = 4 VGPRs
typedef __attribute__((ext_vector_type(4))) float floatx4;  // MFMA C/D

// Fragment-swizzled bf16 Z (4 MB). For row-block rb (16 rows) and k-chunk kk
// (32 k): g_zf[rb*4096 + kk*512 + m*32 + q*8 + j] = Z[rb*16+m][kk*32+q*8+j].
// Unit (rb,kk) = 1 KB, lane-linear (lane = m*4+q reads 16 B at lane*16) ->
// legal as one global_load_lds wave-transfer to a uniform LDS base.
__device__ ushort_t g_zf[M_TOT * DIM];

__device__ __forceinline__ ushort_t f2bf(float f) {  // RNE, finite inputs
    unsigned u = __float_as_uint(f);
    u += 0x7fffu + ((u >> 16) & 1u);
    return (ushort_t)(u >> 16);
}

// ---------------- k_prep: convert(swizzled) + row norms + col sums -----------
// 128 blocks x 256 threads; wave w owns 16 rows; lane l owns cols [4l,4l+4).
__global__ __launch_bounds__(256) void k_prep(const float* __restrict__ X,
                                              const float* __restrict__ Y,
                                              float* __restrict__ sq,
                                              float* __restrict__ colsum_r,
                                              float* __restrict__ Ssum_r) {
    __shared__ float cpart[4][256];
    __shared__ float spart[4];
    const int t = threadIdx.x, wave = t >> 6, lane = t & 63;
    const int row0 = blockIdx.x * 64 + wave * 16;
    const int kk = lane >> 3, q = (lane >> 1) & 3, j0 = (lane & 1) * 4;
    float c0 = 0.f, c1 = 0.f, c2 = 0.f, c3 = 0.f, ssum = 0.f;
#pragma unroll 4
    for (int i = 0; i < 16; ++i) {
        const int row = row0 + i;
        const float* p = (row < N_HALF) ? (X + (size_t)row * DIM)
                                        : (Y + (size_t)(row - N_HALF) * DIM);
        const float4 v = *((const float4*)p + lane);
        ushort4 hi;
        hi.x = f2bf(v.x); hi.y = f2bf(v.y); hi.z = f2bf(v.z); hi.w = f2bf(v.w);
        const int rb = row >> 4, m = row & 15;
        *(ushort4*)(g_zf + (size_t)rb * 4096 + kk * 512 + m * 32 + q * 8 + j0) = hi;
        c0 += v.x; c1 += v.y; c2 += v.z; c3 += v.w;
        float s = fmaf(v.x, v.x, fmaf(v.y, v.y, fmaf(v.z, v.z, v.w * v.w)));
#pragma unroll
        for (int o = 32; o > 0; o >>= 1) s += __shfl_xor(s, o);
        if (lane == 0) sq[row] = s;
        ssum += s;  // butterfly left full sum in every lane
    }
    float4 cp; cp.x = c0; cp.y = c1; cp.z = c2; cp.w = c3;
    *(float4*)&cpart[wave][lane * 4] = cp;
    if (lane == 0) spart[wave] = ssum;
    __syncthreads();
    const float cs = cpart[0][t] + cpart[1][t] + cpart[2][t] + cpart[3][t];
    const int rep = blockIdx.x & 7;  // 8 replicas -> 16 adds/address
    atomicAdd(&colsum_r[rep * 256 + t], cs);  // poison -3e-13/rep: harmless
    if (t == 0) atomicAdd(&Ssum_r[rep], spart[0] + spart[1] + spart[2] + spart[3]);
}

// ---------------- k_bw: bandwidth scalar (1 block) ---------------------------
__global__ __launch_bounds__(256) void k_bw(const float* __restrict__ colsum_r,
                                            const float* __restrict__ Ssum_r,
                                            float* __restrict__ cconst) {
    __shared__ double red[4];
    const int t = threadIdx.x, lane = t & 63, wave = t >> 6;
    float csf = 0.f;
#pragma unroll
    for (int r = 0; r < 8; ++r) csf += colsum_r[r * 256 + t];
    double p = (double)csf * (double)csf;
#pragma unroll
    for (int o = 32; o > 0; o >>= 1) p += __shfl_xor(p, o);
    if (lane == 0) red[wave] = p;
    __syncthreads();
    if (t == 0) {
        const double SS = red[0] + red[1] + red[2] + red[3];
        float Sf = 0.f;
#pragma unroll
        for (int r = 0; r < 8; ++r) Sf += Ssum_r[r];
        const double sum_d2 = 2.0 * (double)M_TOT * (double)Sf - 2.0 * SS;
        const double bw = sum_d2 / ((double)M_TOT * (double)M_TOT - (double)M_TOT);
        cconst[0] = (float)(1.4426950408889634 / (4.0 * bw));  // exp2 scale
    }
}

// ---------------- k_gram: 256x256 LDS-tiled MFMA Gram + finalize -------------
// 528 blocks x 512 threads (8 waves). Wave w: rows [64*(w>>1),+64) x cols
// [128*(w&1),+128) of the tile -> mi=4, ni=8, accv = 32 floatx4 (128 VGPR).
// K-chunk 64: LDS buf = A(32 KB) + B(32 KB); double-buffered = 128 KB.
__global__ __launch_bounds__(512, 2) void k_gram(const float* __restrict__ sq,
                                                 const float* __restrict__ cconst,
                                                 double* __restrict__ acc,
                                                 unsigned* __restrict__ cnt,
                                                 float* __restrict__ out) {
    __shared__ __align__(16) ushort_t Sbuf[2][32768];  // 2 x 64 KB
    __shared__ double redw[8][3];

    const int bid = (int)blockIdx.x;
    const int b = (bid & 7) * 66 + (bid >> 3);  // XCD-band swizzle (528=8*66)
    // triangular decode over NT2=32: b -> (ti, tj), tj >= ti
    int ti = (int)((65.0f - sqrtf(4225.0f - 8.0f * (float)b)) * 0.5f);
    if (ti < 0) ti = 0; if (ti > NT2 - 1) ti = NT2 - 1;
    while (ti * NT2 - ti * (ti - 1) / 2 > b) --ti;
    while ((ti + 1) * NT2 - (ti + 1) * ti / 2 <= b) ++ti;
    const int tj = ti + (b - (ti * NT2 - ti * (ti - 1) / 2));

    const int t = threadIdx.x;
    const int lane = t & 63, wave = t >> 6;
    const int l15 = lane & 15, quad = lane >> 4;
    const int wrow = (wave >> 1) * 64, wcol = (wave & 1) * 128;

    const float c2 = cconst[0];
    const float twoc2 = 2.f * c2;

    // ---- staging: chunk kc has 64 1-KB units: A units 0..31 (rbl*2+kkp),
    // B units 32..63. Each wave stages 8 units; lane contributes 16 B at
    // src + lane*8 elems -> LDS uniform base + lane*16 (DMA-legal).
    const int rbA0 = ti * 16, rbB0 = tj * 16;
    auto stage = [&](int kc, int bufi) {
#pragma unroll
        for (int u8 = 0; u8 < 8; ++u8) {
            const int unit = wave * 8 + u8;            // 0..63
            const int isB = unit >> 5;                 // 0:A, 1:B
            const int u2 = unit & 31;
            const int rbl = u2 >> 1, kkp = u2 & 1;
            const int rb = (isB ? rbB0 : rbA0) + rbl;
            const ushort_t* src = g_zf + (size_t)rb * 4096 +
                                  (kc * 2 + kkp) * 512 + lane * 8;
            __builtin_amdgcn_global_load_lds(
                (const __attribute__((address_space(1))) void*)src,
                (__attribute__((address_space(3))) void*)(&Sbuf[bufi][unit * 512]),
                16, 0, 0);
        }
    };

    floatx4 accv[4][8];
#pragma unroll
    for (int mi = 0; mi < 4; ++mi)
#pragma unroll
        for (int ni = 0; ni < 8; ++ni) accv[mi][ni] = (floatx4)0.f;

    const int fragoff = l15 * 32 + quad * 8;   // within a 1-KB unit (elems)
    const int rblA = (wave >> 1) * 4;          // wave's first A row-block
    const int rblB = (wave & 1) * 8;           // wave's first B row-block

    stage(0, 0);  // prime chunk 0
#pragma unroll
    for (int kc = 0; kc < 4; ++kc) {
        __syncthreads();  // drains stage(kc) (compiler vmcnt) + frees other buf
        if (kc < 3) stage(kc + 1, (kc + 1) & 1);
        const ushort_t* Sb = &Sbuf[kc & 1][0];
#pragma unroll
        for (int kkp = 0; kkp < 2; ++kkp) {
            short8 af[4], bf[8];
#pragma unroll
            for (int mi = 0; mi < 4; ++mi)
                af[mi] = *(const short8*)(Sb + ((rblA + mi) * 2 + kkp) * 512 + fragoff);
#pragma unroll
            for (int ni = 0; ni < 8; ++ni)
                bf[ni] = *(const short8*)(Sb + 16384 +
                                          ((rblB + ni) * 2 + kkp) * 512 + fragoff);
#pragma unroll
            for (int mi = 0; mi < 4; ++mi)
#pragma unroll
                for (int ni = 0; ni < 8; ++ni)
                    accv[mi][ni] = __builtin_amdgcn_mfma_f32_16x16x32_bf16(
                        af[mi], bf[ni], accv[mi][ni], 0, 0, 0);
        }
    }

    // ---- epilogue. C/D: col = lane&15, row = quad*4 + reg. ----
    const int arow0 = ti * TILE2 + wrow, brow0 = tj * TILE2 + wcol;
    float nsj[8];
#pragma unroll
    for (int ni = 0; ni < 8; ++ni)
        nsj[ni] = -c2 * sq[brow0 + ni * 16 + l15];
    floatx4 nsi4[4];
#pragma unroll
    for (int mi = 0; mi < 4; ++mi) {
        const float4 sv = *(const float4*)&sq[arow0 + mi * 16 + quad * 4];
        nsi4[mi][0] = -c2 * sv.x; nsi4[mi][1] = -c2 * sv.y;
        nsi4[mi][2] = -c2 * sv.z; nsi4[mi][3] = -c2 * sv.w;
    }
    floatx4 sum4 = (floatx4)0.f;
#pragma unroll
    for (int mi = 0; mi < 4; ++mi) {
#pragma unroll
        for (int ni = 0; ni < 8; ++ni) {
            const floatx4 addv = nsi4[mi] + (floatx4)nsj[ni];
            floatx4 arg = twoc2 * accv[mi][ni] + addv;
            floatx4 tt;
#pragma unroll
            for (int r = 0; r < 4; ++r) tt[r] = exp2f(fminf(arg[r], 0.f));
            const floatx4 t2 = tt * tt, t4 = t2 * t2, t8 = t4 * t4, t16 = t8 * t8;
            sum4 += (tt + t2) + (t4 + t8) + t16;
        }
    }
    const float fsum = (sum4[0] + sum4[1]) + (sum4[2] + sum4[3]);
    const double contrib = ((ti == tj) ? 1.0 : 2.0) * (double)fsum;
    double lxx = 0.0, lxy = 0.0, lyy = 0.0;
    if (tj < NT2_HALF)       lxx = contrib;   // block-uniform branches
    else if (ti < NT2_HALF)  lxy = contrib;
    else                     lyy = contrib;

    // ---- block reduction + finalize ----
#pragma unroll
    for (int off = 32; off > 0; off >>= 1) {
        lxx += __shfl_xor(lxx, off);
        lxy += __shfl_xor(lxy, off);
        lyy += __shfl_xor(lyy, off);
    }
    if (lane == 0) { redw[wave][0] = lxx; redw[wave][1] = lxy; redw[wave][2] = lyy; }
    __syncthreads();
    if (t == 0) {
        double sxx = 0.0, sxy = 0.0, syy = 0.0;
#pragma unroll
        for (int wv = 0; wv < 8; ++wv) {
            sxx += redw[wv][0]; sxy += redw[wv][1]; syy += redw[wv][2];
        }
        if (sxx != 0.0) atomicAdd(&acc[0], sxx);
        if (sxy != 0.0) atomicAdd(&acc[1], sxy);
        if (syy != 0.0) atomicAdd(&acc[2], syy);
        __threadfence();  // release region adds before counter bump
        const unsigned old = atomicAdd(cnt, 1u);
        // counter starts at 0xAAAAAAAA (ws poison) or 0 — accept either
        if (old == (0xAAAAAAAAu + (unsigned)(NB2 - 1)) ||
            old == (unsigned)(NB2 - 1)) {
            const double xx = atomicAdd(&acc[0], 0.0);  // coherent reads
            const double xy = atomicAdd(&acc[1], 0.0);
            const double yy = atomicAdd(&acc[2], 0.0);
            out[0] = (float)((xx + yy - xy) *
                             (1.0 / ((double)N_HALF * (double)N_HALF)));
        }
    }
}

extern "C" void kernel_launch(void* const* d_in, const int* in_sizes, int n_in,
                              void* d_out, int out_size, void* d_ws, size_t ws_size,
                              hipStream_t stream) {
    const float* X = (const float*)d_in[0];
    const float* Y = (const float*)d_in[1];
    char* ws = (char*)d_ws;
    float* sq        = (float*)ws;               // 8192 f32  [0, 32768)
    float* colsum_r  = (float*)(ws + 32768);     // 8*256 f32 [32768, 40960)
    float* Ssum_r    = (float*)(ws + 40960);     // 8 f32     [40960, 40992)
    unsigned* cnt    = (unsigned*)(ws + 40992);  // 1 u32
    double* acc      = (double*)(ws + 41000);    // 3 f64 (8-aligned)
    float* cconst    = (float*)(ws + 41024);     // 1 f32
    float* out = (float*)d_out;

    hipLaunchKernelGGL(k_prep, dim3(128), dim3(256), 0, stream,
                       X, Y, sq, colsum_r, Ssum_r);
    hipLaunchKernelGGL(k_bw, dim3(1), dim3(256), 0, stream,
                       colsum_r, Ssum_r, cconst);
    hipLaunchKernelGGL(k_gram, dim3(NB2), dim3(512), 0, stream,
                       sq, cconst, acc, cnt, out);
}